// Round 5
// baseline (316.883 us; speedup 1.0000x reference)
//
#include <hip/hip_runtime.h>

// Transformer block. B=2 T=2048 E=1024 H=16 DH=64.
// R17: gemm256 un-pinned. The sched_barrier(0) I had inside PHASE_MID
// (defensive, rule #18) forced a full lgkmcnt(0) drain before any MFMA,
// defeating the compiler's partial-wait interleave (the verified m201
// template has no sched_barrier; rule #18 only applies to inline-asm
// ds_reads). Also precompute the 24 swizzled LDS read offsets into
// statically-indexed register arrays (HK prefill_swizzled_offsets).
// Attention (R15 swapped-QK) and everything else unchanged.

#define En 1024
#define Hn 16
#define DHn 64
#define Bn 2
#define Tn 2048
#define Mrows 4096  // B*T

typedef __attribute__((ext_vector_type(8))) short bf16x8;
typedef __attribute__((ext_vector_type(4))) float f32x4;

__device__ __forceinline__ short f2bf(float f) {
    unsigned u = __float_as_uint(f);
    u += 0x7FFFu + ((u >> 16) & 1u);   // round-to-nearest-even
    return (short)(u >> 16);
}
__device__ __forceinline__ ushort f2bfu(float f) {
    unsigned u = __float_as_uint(f);
    u += 0x7FFFu + ((u >> 16) & 1u);
    return (ushort)(u >> 16);
}
__device__ __forceinline__ float bf2f(ushort u) {
    return __uint_as_float((unsigned)u << 16);
}
__device__ __forceinline__ unsigned cvt_pk_bf16(float lo, float hi) {
    unsigned r;
    asm("v_cvt_pk_bf16_f32 %0, %1, %2" : "=v"(r) : "v"(lo), "v"(hi));
    return r;
}

// gelu = 0.5*x*(1+tanh(u)) = x * t/(t+1), t = exp(2u); u = c*x + 0.044715*x^3
__device__ __forceinline__ float gelu_f(float x) {
    float u = 0.79788456080286535588f * x + 0.044715f * x * x * x;
    float t = __expf(2.0f * u);
    return x * t / (t + 1.0f);
}

// async global->LDS, 16B per lane; LDS dest = wave-uniform base + lane*16
__device__ __forceinline__ void load_lds16(const void* g, void* l) {
    __builtin_amdgcn_global_load_lds(
        (const __attribute__((address_space(1))) unsigned int*)(uintptr_t)g,
        (__attribute__((address_space(3))) unsigned int*)(uintptr_t)l,
        16, 0, 0);
}

// ---------------- LayerNorm: one block per row, bf16 out ----------------
__global__ __launch_bounds__(256) void ln_kernel(
    const float* __restrict__ in, const float* __restrict__ sc,
    const float* __restrict__ sh, ushort* __restrict__ out)
{
    int row = blockIdx.x;
    int tid = threadIdx.x;
    float4 v = ((const float4*)(in + (size_t)row * En))[tid];
    float s  = v.x + v.y + v.z + v.w;
    float s2 = v.x*v.x + v.y*v.y + v.z*v.z + v.w*v.w;
    #pragma unroll
    for (int off = 32; off > 0; off >>= 1) {
        s  += __shfl_down(s,  off);
        s2 += __shfl_down(s2, off);
    }
    __shared__ float red[2][4];
    int wave = tid >> 6, lane = tid & 63;
    if (lane == 0) { red[0][wave] = s; red[1][wave] = s2; }
    __syncthreads();
    s  = red[0][0] + red[0][1] + red[0][2] + red[0][3];
    s2 = red[1][0] + red[1][1] + red[1][2] + red[1][3];
    float mean = s * (1.0f / En);
    float var  = s2 * (1.0f / En) - mean * mean;
    float r = rsqrtf(var + 1e-5f);
    float4 scv = ((const float4*)sc)[tid];
    float4 shv = ((const float4*)sh)[tid];
    ushort4 o;
    o.x = f2bfu(scv.x * (v.x - mean) * r + shv.x);
    o.y = f2bfu(scv.y * (v.y - mean) * r + shv.y);
    o.z = f2bfu(scv.z * (v.z - mean) * r + shv.z);
    o.w = f2bfu(scv.w * (v.w - mean) * r + shv.w);
    ((ushort4*)(out + (size_t)row * En))[tid] = o;
}

// ---- fc split-K reduce (bf16 partials) + residual + LN2; h stored bf16 ----
__global__ __launch_bounds__(256) void ln2_fuse(
    const ushort* __restrict__ P0, const ushort* __restrict__ P1,
    const float* __restrict__ bias, const float* __restrict__ x,
    const float* __restrict__ sc, const float* __restrict__ sh,
    ushort* __restrict__ hb, ushort* __restrict__ ynb)
{
    int row = blockIdx.x, tid = threadIdx.x;
    size_t idx = (size_t)row * 256 + tid;
    ushort4 a = ((const ushort4*)P0)[idx];
    ushort4 b = ((const ushort4*)P1)[idx];
    float4 bi = ((const float4*)bias)[tid];
    float4 xr = ((const float4*)x)[idx];
    float4 v;
    v.x = bf2f(a.x) + bf2f(b.x) + bi.x + xr.x;
    v.y = bf2f(a.y) + bf2f(b.y) + bi.y + xr.y;
    v.z = bf2f(a.z) + bf2f(b.z) + bi.z + xr.z;
    v.w = bf2f(a.w) + bf2f(b.w) + bi.w + xr.w;
    ushort4 hv;
    hv.x = f2bfu(v.x); hv.y = f2bfu(v.y); hv.z = f2bfu(v.z); hv.w = f2bfu(v.w);
    ((ushort4*)hb)[idx] = hv;
    float s  = v.x + v.y + v.z + v.w;
    float s2 = v.x*v.x + v.y*v.y + v.z*v.z + v.w*v.w;
    #pragma unroll
    for (int off = 32; off > 0; off >>= 1) {
        s  += __shfl_down(s,  off);
        s2 += __shfl_down(s2, off);
    }
    __shared__ float red[2][4];
    int wave = tid >> 6, lane = tid & 63;
    if (lane == 0) { red[0][wave] = s; red[1][wave] = s2; }
    __syncthreads();
    s  = red[0][0] + red[0][1] + red[0][2] + red[0][3];
    s2 = red[1][0] + red[1][1] + red[1][2] + red[1][3];
    float mean = s * (1.0f / En);
    float var  = s2 * (1.0f / En) - mean * mean;
    float r = rsqrtf(var + 1e-5f);
    float4 scv = ((const float4*)sc)[tid];
    float4 shv = ((const float4*)sh)[tid];
    ushort4 o;
    o.x = f2bfu(scv.x * (v.x - mean) * r + shv.x);
    o.y = f2bfu(scv.y * (v.y - mean) * r + shv.y);
    o.z = f2bfu(scv.z * (v.z - mean) * r + shv.z);
    o.w = f2bfu(scv.w * (v.w - mean) * r + shv.w);
    ((ushort4*)ynb)[idx] = o;
}

// ---- ff2 split-K=4 reduce (bf16 partials) + bias + residual(bf16 h) -> out --
__global__ __launch_bounds__(256) void ff2_reduce4(
    const ushort* __restrict__ P, const float* __restrict__ bias,
    const ushort* __restrict__ hb, float* __restrict__ out)
{
    int tid = threadIdx.x;
    size_t i = (size_t)blockIdx.x * 256 + tid;
    const size_t S = (size_t)Mrows * En / 4;   // ushort4 per partial
    ushort4 a = ((const ushort4*)P)[i];
    ushort4 b = ((const ushort4*)P)[i + S];
    ushort4 c = ((const ushort4*)P)[i + 2 * S];
    ushort4 d = ((const ushort4*)P)[i + 3 * S];
    float4 bi = ((const float4*)bias)[tid];
    ushort4 hu = ((const ushort4*)hb)[i];
    float4 o;
    o.x = (bf2f(a.x) + bf2f(b.x)) + (bf2f(c.x) + bf2f(d.x)) + bi.x + bf2f(hu.x);
    o.y = (bf2f(a.y) + bf2f(b.y)) + (bf2f(c.y) + bf2f(d.y)) + bi.y + bf2f(hu.y);
    o.z = (bf2f(a.z) + bf2f(b.z)) + (bf2f(c.z) + bf2f(d.z)) + bi.z + bf2f(hu.z);
    o.w = (bf2f(a.w) + bf2f(b.w)) + (bf2f(c.w) + bf2f(d.w)) + bi.w + bf2f(hu.w);
    ((float4*)out)[i] = o;
}

// ------- unified weight prep: all four transposes in one dispatch ---------
// out[n*ldo + k] = bf16(in[k*N + n]), 64x64 tiles.
__global__ __launch_bounds__(256) void prep_w(
    const float* __restrict__ Wq, const float* __restrict__ Wk,
    const float* __restrict__ Wv, const float* __restrict__ fc_w,
    const float* __restrict__ ff_w1, const float* __restrict__ ff_w2,
    ushort* __restrict__ wqkv, ushort* __restrict__ wfc,
    ushort* __restrict__ wf1, ushort* __restrict__ wf2)
{
    int bid = blockIdx.x;
    const float* in; ushort* out; int N, ldo, k0, n0;
    if (bid < 768) {                       // qkv: 48 z-slices x 16 k-blocks
        int z = bid >> 4, kb = bid & 15;
        int sel = z / 16, h = z % 16;
        in  = (sel == 0 ? Wq : sel == 1 ? Wk : Wv) + (size_t)h * En * DHn;
        out = wqkv + (size_t)(sel * 1024 + h * 64) * En;
        N = DHn; ldo = En; k0 = kb * 64; n0 = 0;
    } else if (bid < 1024) {               // fc_w: 16x16
        int b2 = bid - 768;
        in = fc_w; out = wfc; N = En; ldo = En;
        k0 = (b2 & 15) * 64; n0 = (b2 >> 4) * 64;
    } else if (bid < 2048) {               // ff_w1: 16 k x 64 n
        int b2 = bid - 1024;
        in = ff_w1; out = wf1; N = 4 * En; ldo = En;
        k0 = (b2 & 15) * 64; n0 = (b2 >> 4) * 64;
    } else {                               // ff_w2: 64 k x 16 n
        int b2 = bid - 2048;
        in = ff_w2; out = wf2; N = En; ldo = 4 * En;
        k0 = (b2 & 63) * 64; n0 = (b2 >> 6) * 64;
    }
    __shared__ float t[64][65];
    int tid = threadIdx.x, r = tid >> 4, c4 = (tid & 15) * 4;
    #pragma unroll
    for (int i = 0; i < 4; ++i) {
        float4 v = *(const float4*)(in + (size_t)(k0 + r + i * 16) * N + n0 + c4);
        t[r + i * 16][c4 + 0] = v.x; t[r + i * 16][c4 + 1] = v.y;
        t[r + i * 16][c4 + 2] = v.z; t[r + i * 16][c4 + 3] = v.w;
    }
    __syncthreads();
    #pragma unroll
    for (int i = 0; i < 4; ++i) {
        int n = r + i * 16;
        ushort4 u;
        u.x = f2bfu(t[c4 + 0][n]); u.y = f2bfu(t[c4 + 1][n]);
        u.z = f2bfu(t[c4 + 2][n]); u.w = f2bfu(t[c4 + 3][n]);
        *(ushort4*)(out + (size_t)(n0 + n) * ldo + k0 + c4) = u;
    }
}

// ---------------- bf16 MFMA GEMM (old 128-tile): used for fc only ----------
template<int MODE, int TN>
__global__ __launch_bounds__(256) void gemm_bf16(
    const ushort* __restrict__ A, int lda,
    const ushort* __restrict__ Bt, int ldb, int Kloop,
    const float* __restrict__ bias,
    ushort* __restrict__ Cb, int ldc,
    ushort* __restrict__ qo, ushort* __restrict__ ko, ushort* __restrict__ vo)
{
    constexpr int WCN = TN / 2;        // wave n-extent
    constexpr int NI  = WCN / 16;      // 16-col blocks per wave
    constexpr int BIW = TN * 8 / 256;  // B staging instrs per wave
    constexpr int STAGE = 128 * 64 + TN * 64;
    constexpr int BOUNCE = (MODE == 2 || MODE == 1) ? 4 * 64 * 68
                         : (MODE == 3 ? 128 * 68 : 0);
    constexpr int SMEMN = STAGE > BOUNCE ? STAGE : BOUNCE;
    __shared__ ushort smem[SMEMN];
    ushort* As = smem;
    ushort* Bs = smem + 128 * 64;
    int tid = threadIdx.x, wv = tid >> 6, lid = tid & 63;
    int m0 = blockIdx.x * 128, n0 = blockIdx.y * TN;
    int koff = blockIdx.z * Kloop;
    int wr = wv >> 1, wc = wv & 1;
    int hm = lid & 15, hk = lid >> 4;

    f32x4 acc[4][NI];
    #pragma unroll
    for (int i = 0; i < 4; ++i)
        #pragma unroll
        for (int j = 0; j < NI; ++j) acc[i][j] = (f32x4){0.f, 0.f, 0.f, 0.f};

    const ushort* Abase = A + (size_t)m0 * lda + koff;
    const ushort* Bbase = Bt + (size_t)n0 * ldb + koff;

    for (int k0 = 0; k0 < Kloop; k0 += 64) {
        __syncthreads();
        #pragma unroll
        for (int i = 0; i < 4; ++i) {       // A: 1024 chunks, 4/lane
            int c = wv * 256 + i * 64 + lid;
            int r = c >> 3, s = c & 7;
            int j = s ^ (r & 7);            // source k-chunk for this LDS slot
            load_lds16(Abase + (size_t)r * lda + k0 + j * 8,
                       &As[(wv * 256 + i * 64) * 8]);
        }
        #pragma unroll
        for (int i = 0; i < BIW; ++i) {
            int c = wv * (BIW * 64) + i * 64 + lid;
            int r = c >> 3, s = c & 7;
            int j = s ^ (r & 7);
            load_lds16(Bbase + (size_t)r * ldb + k0 + j * 8,
                       &Bs[(wv * (BIW * 64) + i * 64) * 8]);
        }
        __syncthreads();
        #pragma unroll
        for (int kk = 0; kk < 2; ++kk) {
            bf16x8 af[4], bfr[NI];
            #pragma unroll
            for (int mi = 0; mi < 4; ++mi) {
                int r = wr * 64 + mi * 16 + hm;
                int slot = ((kk << 2) | hk) ^ (r & 7);
                af[mi] = *(const bf16x8*)&As[(r * 8 + slot) * 8];
            }
            #pragma unroll
            for (int ni = 0; ni < NI; ++ni) {
                int r = wc * WCN + ni * 16 + hm;
                int slot = ((kk << 2) | hk) ^ (r & 7);
                bfr[ni] = *(const bf16x8*)&Bs[(r * 8 + slot) * 8];
            }
            #pragma unroll
            for (int mi = 0; mi < 4; ++mi)
                #pragma unroll
                for (int ni = 0; ni < NI; ++ni)
                    acc[mi][ni] = __builtin_amdgcn_mfma_f32_16x16x32_bf16(
                        af[mi], bfr[ni], acc[mi][ni], 0, 0, 0);
        }
    }

    int colbase = n0 + wc * WCN + hm;
    if (MODE == 1) {
        __syncthreads();
        ushort* Ls = smem + wv * (64 * 68);
        #pragma unroll
        for (int ni = 0; ni < NI; ++ni) {
            int col = colbase + ni * 16;
            float bb = bias[col];
            #pragma unroll
            for (int mi = 0; mi < 4; ++mi)
                #pragma unroll
                for (int r = 0; r < 4; ++r)
                    Ls[(mi * 16 + hk * 4 + r) * 68 + ni * 16 + hm] =
                        f2bfu(gelu_f(acc[mi][ni][r] + bb));
        }
        ushort* outp = Cb + (size_t)(m0 + wr * 64) * ldc + n0 + wc * 64;
        int dcol = hm * 4;
        #pragma unroll
        for (int i = 0; i < 16; ++i) {
            int t = hk + i * 4;
            *(ushort4*)(outp + (size_t)t * ldc + dcol) =
                *(const ushort4*)&Ls[t * 68 + dcol];
        }
    } else if (MODE == 2) {
        __syncthreads();
        ushort* Ls = smem + wv * (64 * 68);
        int col0 = n0 + wc * 64;
        int sel = col0 >> 10, h = (col0 & 1023) >> 6;
        if (sel < 2) {
            #pragma unroll
            for (int ni = 0; ni < NI; ++ni)
                #pragma unroll
                for (int mi = 0; mi < 4; ++mi)
                    #pragma unroll
                    for (int r = 0; r < 4; ++r)
                        Ls[(mi * 16 + hk * 4 + r) * 68 + ni * 16 + hm] =
                            f2bfu(acc[mi][ni][r]);
            ushort* outp = (sel == 0 ? qo : ko) + (size_t)h * (Mrows * DHn);
            int dcol = hm * 4;
            #pragma unroll
            for (int i = 0; i < 16; ++i) {
                int t = hk + i * 4;
                *(ushort4*)(outp + (size_t)(m0 + wr * 64 + t) * DHn + dcol) =
                    *(const ushort4*)&Ls[t * 68 + dcol];
            }
        } else {
            #pragma unroll
            for (int ni = 0; ni < NI; ++ni)
                #pragma unroll
                for (int mi = 0; mi < 4; ++mi)
                    #pragma unroll
                    for (int r = 0; r < 4; ++r)
                        Ls[(ni * 16 + hm) * 68 + mi * 16 + hk * 4 + r] =
                            f2bfu(acc[mi][ni][r]);
            int bb2 = m0 >> 11;                 // batch of this row-tile
            int t0 = (m0 & 2047) + wr * 64;
            ushort* outp = vo + ((size_t)((h * 2 + bb2) * 64)) * Tn + t0;
            int tcol = hm * 4;
            #pragma unroll
            for (int i = 0; i < 16; ++i) {
                int d = hk + i * 4;
                *(ushort4*)(outp + (size_t)d * Tn + tcol) =
                    *(const ushort4*)&Ls[d * 68 + tcol];
            }
        }
    } else {
        __syncthreads();
        ushort* Ls = smem;
        #pragma unroll
        for (int ni = 0; ni < NI; ++ni)
            #pragma unroll
            for (int mi = 0; mi < 4; ++mi)
                #pragma unroll
                for (int r = 0; r < 4; ++r)
                    Ls[(wr * 64 + mi * 16 + hk * 4 + r) * 68
                       + wc * WCN + ni * 16 + hm] = f2bfu(acc[mi][ni][r]);
        __syncthreads();
        ushort* Cp = Cb + (size_t)blockIdx.z * Mrows * ldc;
        #pragma unroll
        for (int it = 0; it < 8; ++it) {
            int i = it * 1024 + tid * 4;
            int row = i >> 6, col = i & 63;
            *(ushort4*)(Cp + (size_t)(m0 + row) * ldc + n0 + col) =
                *(const ushort4*)&Ls[row * 68 + col];
        }
    }
}

// ============ gemm256: 256x256 tile, BK=64, 8-phase counted-vmcnt ==========
// R17: no sched_barrier in PHASE_MID (match verified m201 template; let the
// compiler emit partial lgkmcnt waits and interleave reads with MFMA).
#define PHASE_MID() do { \
    __builtin_amdgcn_s_barrier(); \
    asm volatile("s_waitcnt lgkmcnt(0)" ::: "memory"); \
} while (0)

#define LOAD_AF(MH, KK) \
    _Pragma("unroll") \
    for (int mi = 0; mi < 4; ++mi) \
        af[mi] = *(const bf16x8*)&As_[offA[MH][KK][mi]];

#define MFMA_PHASE(MH, KK) do { \
    __builtin_amdgcn_s_setprio(1); \
    _Pragma("unroll") \
    for (int mi = 0; mi < 4; ++mi) \
        _Pragma("unroll") \
        for (int ni = 0; ni < 4; ++ni) \
            acc[(MH) * 4 + mi][ni] = __builtin_amdgcn_mfma_f32_16x16x32_bf16( \
                af[mi], bfr[KK][ni], acc[(MH) * 4 + mi][ni], 0, 0, 0); \
    __builtin_amdgcn_s_setprio(0); \
} while (0)

#define STAGE_A(bufp, h, ksrc) do { \
    ushort* _d = smem + (bufp) * 32768; \
    load_lds16(Abase + aoff[h][0] + (ksrc), _d + ldsoff[h][0]); \
    load_lds16(Abase + aoff[h][1] + (ksrc), _d + ldsoff[h][1]); \
} while (0)

#define STAGE_B(bufp, h, ksrc) do { \
    ushort* _d = smem + (bufp) * 32768 + 16384; \
    load_lds16(Bbase + boff[h][0] + (ksrc), _d + ldsoff[h][0]); \
    load_lds16(Bbase + boff[h][1] + (ksrc), _d + ldsoff[h][1]); \
} while (0)

// MODE 1: Cb = bf16(gelu(acc + bias)) row-major [M][ldc]
// MODE 2: qkv scatter (q/k [h][t][d], v^T [g][d][t])
// MODE 3: bf16 split-K partial at Cb + z*Mrows*ldc
template<int MODE>
__global__ __launch_bounds__(512, 2) void gemm256(
    const ushort* __restrict__ A, int lda,
    const ushort* __restrict__ Bt, int ldb, int Kloop,
    const float* __restrict__ bias,
    ushort* __restrict__ Cb, int ldc,
    ushort* __restrict__ qo, ushort* __restrict__ ko, ushort* __restrict__ vo)
{
    __shared__ ushort smem[65536];   // 128 KiB
    int tid = threadIdx.x, wv = tid >> 6, lid = tid & 63;
    int wr = wv >> 2, wc = wv & 3;           // 2M x 4N waves
    int hm = lid & 15, hk = lid >> 4;
    int m0 = blockIdx.x * 256, n0 = blockIdx.y * 256;
    int koff = blockIdx.z * Kloop;
    int NT = Kloop >> 6;

    const ushort* Abase = A + (size_t)m0 * lda + koff;
    const ushort* Bbase = Bt + (size_t)n0 * ldb + koff;

    // per-thread staging offsets: half h, instr i -> chunk c, row r, slot s
    int aoff[2][2], boff[2][2], ldsoff[2][2];
    #pragma unroll
    for (int h = 0; h < 2; ++h)
        #pragma unroll
        for (int i = 0; i < 2; ++i) {
            int c = h * 1024 + wv * 128 + i * 64 + lid;
            int r = c >> 3, s = c & 7, j = s ^ (r & 7);
            aoff[h][i] = r * lda + j * 8;
            boff[h][i] = r * ldb + j * 8;
            ldsoff[h][i] = (h * 1024 + wv * 128 + i * 64) * 8;  // wave-uniform
        }

    // precomputed swizzled LDS read offsets (all statically indexed)
    int offA[2][2][4], offB[2][4];
    #pragma unroll
    for (int mh = 0; mh < 2; ++mh)
        #pragma unroll
        for (int kk = 0; kk < 2; ++kk)
            #pragma unroll
            for (int mi = 0; mi < 4; ++mi) {
                int r = wr * 128 + mh * 64 + mi * 16 + hm;
                offA[mh][kk][mi] = (r * 8 + (((kk << 2) | hk) ^ (r & 7))) * 8;
            }
    #pragma unroll
    for (int kk = 0; kk < 2; ++kk)
        #pragma unroll
        for (int ni = 0; ni < 4; ++ni) {
            int r = wc * 64 + ni * 16 + hm;
            offB[kk][ni] = (r * 8 + (((kk << 2) | hk) ^ (r & 7))) * 8;
        }

    f32x4 acc[8][4];
    #pragma unroll
    for (int i = 0; i < 8; ++i)
        #pragma unroll
        for (int j = 0; j < 4; ++j) acc[i][j] = (f32x4){0.f, 0.f, 0.f, 0.f};

    // prologue: A0, B0 -> buf0; B1 -> buf1; allow B1 (4 loads) outstanding
    STAGE_A(0, 0, 0); STAGE_A(0, 1, 0);
    STAGE_B(0, 0, 0); STAGE_B(0, 1, 0);
    {
        int k1 = (NT > 1 ? 1 : 0) << 6;
        STAGE_B(1, 0, k1); STAGE_B(1, 1, k1);
    }
    asm volatile("s_waitcnt vmcnt(4)" ::: "memory");
    __builtin_amdgcn_s_barrier();

    for (int t = 0; t < NT; ++t) {
        int cur = t & 1, nxt = cur ^ 1;
        int kA = (t + 1 < NT ? t + 1 : NT - 1) << 6;   // clamp: tail issues
        int kB = (t + 2 < NT ? t + 2 : NT - 1) << 6;   // harmless re-reads
        const ushort* As_ = smem + cur * 32768;
        const ushort* Bs_ = As_ + 16384;
        bf16x8 af[4], bfr[2][4];

        // ---- phase 1: mh0 x kk0; read all B frags; stage A(t+1) h0 ----
        LOAD_AF(0, 0);
        #pragma unroll
        for (int kk = 0; kk < 2; ++kk)
            #pragma unroll
            for (int ni = 0; ni < 4; ++ni)
                bfr[kk][ni] = *(const bf16x8*)&Bs_[offB[kk][ni]];
        STAGE_A(nxt, 0, kA);
        PHASE_MID();
        MFMA_PHASE(0, 0);
        __builtin_amdgcn_s_barrier();

        // ---- phase 2: mh1 x kk0; stage A(t+1) h1 ----
        LOAD_AF(1, 0);
        STAGE_A(nxt, 1, kA);
        PHASE_MID();
        MFMA_PHASE(1, 0);
        __builtin_amdgcn_s_barrier();

        // ---- phase 3: mh0 x kk1; stage B(t+2) h0 (into current buf) ----
        LOAD_AF(0, 1);
        STAGE_B(cur, 0, kB);
        PHASE_MID();
        MFMA_PHASE(0, 1);
        __builtin_amdgcn_s_barrier();

        // ---- phase 4: mh1 x kk1; stage B(t+2) h1; counted boundary wait ----
        LOAD_AF(1, 1);
        STAGE_B(cur, 1, kB);
        PHASE_MID();
        MFMA_PHASE(1, 1);
        asm volatile("s_waitcnt vmcnt(4)" ::: "memory");
        __builtin_amdgcn_s_barrier();
    }
    // drain trailing (garbage) stages before LDS reuse by epilogue
    asm volatile("s_waitcnt vmcnt(0)" ::: "memory");
    __builtin_amdgcn_s_barrier();

    // ---------------- epilogues: per-wave 64x68 LDS bounce, 2 chunks -------
    ushort* Ls = smem + wv * (64 * 68);
    int dcol = hm * 4;
    if (MODE == 1) {
        float bb[4];
        #pragma unroll
        for (int ni = 0; ni < 4; ++ni) bb[ni] = bias[n0 + wc * 64 + ni * 16 + hm];
        #pragma unroll
        for (int mh = 0; mh < 2; ++mh) {
            #pragma unroll
            for (int ni = 0; ni < 4; ++ni)
                #pragma unroll
                for (int mi = 0; mi < 4; ++mi)
                    #pragma unroll
                    for (int r = 0; r < 4; ++r)
                        Ls[(mi * 16 + hk * 4 + r) * 68 + ni * 16 + hm] =
                            f2bfu(gelu_f(acc[mh * 4 + mi][ni][r] + bb[ni]));
            ushort* outp = Cb + (size_t)(m0 + wr * 128 + mh * 64) * ldc
                              + n0 + wc * 64;
            #pragma unroll
            for (int i = 0; i < 16; ++i) {
                int tt = hk + i * 4;
                *(ushort4*)(outp + (size_t)tt * ldc + dcol) =
                    *(const ushort4*)&Ls[tt * 68 + dcol];
            }
        }
    } else if (MODE == 2) {
        int col0 = n0 + wc * 64;
        int sel = col0 >> 10, hh = (col0 & 1023) >> 6;
        #pragma unroll
        for (int mh = 0; mh < 2; ++mh) {
            int rowb = m0 + wr * 128 + mh * 64;
            if (sel < 2) {
                #pragma unroll
                for (int ni = 0; ni < 4; ++ni)
                    #pragma unroll
                    for (int mi = 0; mi < 4; ++mi)
                        #pragma unroll
                        for (int r = 0; r < 4; ++r)
                            Ls[(mi * 16 + hk * 4 + r) * 68 + ni * 16 + hm] =
                                f2bfu(acc[mh * 4 + mi][ni][r]);
                ushort* outp = (sel == 0 ? qo : ko) + (size_t)hh * (Mrows * DHn);
                #pragma unroll
                for (int i = 0; i < 16; ++i) {
                    int tt = hk + i * 4;
                    *(ushort4*)(outp + (size_t)(rowb + tt) * DHn + dcol) =
                        *(const ushort4*)&Ls[tt * 68 + dcol];
                }
            } else {
                #pragma unroll
                for (int ni = 0; ni < 4; ++ni)
                    #pragma unroll
                    for (int mi = 0; mi < 4; ++mi)
                        #pragma unroll
                        for (int r = 0; r < 4; ++r)
                            Ls[(ni * 16 + hm) * 68 + mi * 16 + hk * 4 + r] =
                                f2bfu(acc[mh * 4 + mi][ni][r]);
                int bb2 = m0 >> 11;
                int t0 = (m0 & 2047) + wr * 128 + mh * 64;
                ushort* outp = vo + ((size_t)((hh * 2 + bb2) * 64)) * Tn + t0;
                #pragma unroll
                for (int i = 0; i < 16; ++i) {
                    int d = hk + i * 4;
                    *(ushort4*)(outp + (size_t)d * Tn + dcol) =
                        *(const ushort4*)&Ls[d * 68 + dcol];
                }
            }
        }
    } else {
        ushort* Cp = Cb + (size_t)blockIdx.z * ((size_t)Mrows * ldc);
        #pragma unroll
        for (int mh = 0; mh < 2; ++mh) {
            #pragma unroll
            for (int ni = 0; ni < 4; ++ni)
                #pragma unroll
                for (int mi = 0; mi < 4; ++mi)
                    #pragma unroll
                    for (int r = 0; r < 4; ++r)
                        Ls[(mi * 16 + hk * 4 + r) * 68 + ni * 16 + hm] =
                            f2bfu(acc[mh * 4 + mi][ni][r]);
            ushort* outp = Cp + (size_t)(m0 + wr * 128 + mh * 64) * ldc
                              + n0 + wc * 64;
            #pragma unroll
            for (int i = 0; i < 16; ++i) {
                int tt = hk + i * 4;
                *(ushort4*)(outp + (size_t)tt * ldc + dcol) =
                    *(const ushort4*)&Ls[tt * 68 + dcol];
            }
        }
    }
}

// ======== MFMA flash attention v5: swapped QK^T + packed P bounce ==========
// Grid (32, 8), 512 thr. Per round: TWO k-tiles staged/computed, one barrier.
// Swapped QK: acc2 = mfma(kf, qf) -> P[key=ct*16+gq*4+r][q=m]. Softmax row
// values are 4-consecutive-key groups per lane: pack with v_cvt_pk_bf16_f32,
// write 4x ds_write_b64 into Ps[q][key] (slot-XOR swizzled), read back as
// standard A-frags (2x ds_read_b128). lsum is one scalar per lane (q=m);
// epilogue reduces across gq groups (2 shfl_xor) + redistributes (4 shfl).
__global__ __launch_bounds__(512) void attn_mfma(
    const ushort* __restrict__ q, const ushort* __restrict__ ksrc,
    const ushort* __restrict__ vtsrc, ushort* __restrict__ cat)
{
    int g = blockIdx.x;
    int h = g >> 1, b = g & 1;
    const ushort* qg  = q     + (size_t)g * Tn * DHn;
    const ushort* kg  = ksrc  + (size_t)g * Tn * DHn;
    const ushort* vtg = vtsrc + (size_t)g * DHn * Tn;   // [d][t]
    int tid = threadIdx.x, w = tid >> 6, lane = tid & 63;
    int m = lane & 15, gq = lane >> 4;
    int qoff = gq * 4;

    __shared__ short Ks[2][2][4096];   // [buf][tile-half][key(64)][d(64)] swz
    __shared__ short Vt[2][2][4096];   // [buf][tile-half][d(64)][key(64)] swz
    __shared__ short Ps[8][1024];      // per-wave [q(16)][key(64)] swz

    int R = tid >> 3;    // staging row 0..63
    int c = tid & 7;     // staging 8-ushort chunk
    int slot = R * 64 + ((c ^ (R & 7)) << 3);
    const ushort* kbase = kg  + (size_t)R * DHn + c * 8;  // + kt*4096
    const ushort* vbase = vtg + (size_t)R * Tn  + c * 8;  // + kt*64

    #pragma unroll 1
    for (int phase = 0; phase < 2; ++phase) {
        int qj = phase ? (15 - (int)blockIdx.y) : (int)blockIdx.y;
        int q0 = qj * 128;
        int NR = qj + 1;                 // rounds of 2 k-tiles
        int qb = q0 + w * 16;            // wave's first q row

        bf16x8 qf[2];
        {
            const ushort* qp = qg + (size_t)(qb + m) * DHn + gq * 8;
            qf[0] = *(const bf16x8*)(qp);
            qf[1] = *(const bf16x8*)(qp + 32);
        }
        f32x4 o[4];
        #pragma unroll
        for (int i = 0; i < 4; ++i) o[i] = (f32x4){0.f, 0.f, 0.f, 0.f};
        float lsum = 0.f;

        // prologue: stage tiles 0,1 into buf0
        {
            bf16x8 a0 = *(const bf16x8*)(kbase);
            bf16x8 a1 = *(const bf16x8*)(kbase + 4096);
            bf16x8 b0 = *(const bf16x8*)(vbase);
            bf16x8 b1 = *(const bf16x8*)(vbase + 64);
            *(bf16x8*)&Ks[0][0][slot] = a0;
            *(bf16x8*)&Ks[0][1][slot] = a1;
            *(bf16x8*)&Vt[0][0][slot] = b0;
            *(bf16x8*)&Vt[0][1][slot] = b1;
        }
        __syncthreads();

        #pragma unroll 1
        for (int rd = 0; rd < NR; ++rd) {
            int cur = rd & 1;
            bf16x8 k0r, k1r, v0r, v1r;
            bool pre = (rd + 1 < NR);
            if (pre) {   // issue prefetch BEFORE compute (T14)
                k0r = *(const bf16x8*)(kbase + (size_t)(2 * rd + 2) * 4096);
                k1r = *(const bf16x8*)(kbase + (size_t)(2 * rd + 3) * 4096);
                v0r = *(const bf16x8*)(vbase + (2 * rd + 2) * 64);
                v1r = *(const bf16x8*)(vbase + (2 * rd + 3) * 64);
            }
            #pragma unroll
            for (int hf = 0; hf < 2; ++hf) {
                int kt = 2 * rd + hf;
                const short* Kt_ = &Ks[cur][hf][0];
                const short* Vt_ = &Vt[cur][hf][0];
                if (qb < kt * 64) continue;   // wave fully masked here

                // ---- QK^T swapped: P[key][q], 4 consecutive keys/lane ----
                #pragma unroll
                for (int ct = 0; ct < 4; ++ct) {
                    int dk2 = kt * 64 + ct * 16 - qb;   // wave-uniform, %16==0
                    uint2 u;
                    if (dk2 > 0) {
                        u.x = 0u; u.y = 0u;
                    } else {
                        f32x4 acc = (f32x4){0.f, 0.f, 0.f, 0.f};
                        int row = ct * 16 + m;     // key within tile
                        __builtin_amdgcn_s_setprio(1);
                        #pragma unroll
                        for (int db = 0; db < 2; ++db) {
                            bf16x8 kf = *(const bf16x8*)
                                &Kt_[row * 64 + (((db * 4 + gq) ^ (row & 7)) << 3)];
                            acc = __builtin_amdgcn_mfma_f32_16x16x32_bf16(
                                kf, qf[db], acc, 0, 0, 0);
                        }
                        __builtin_amdgcn_s_setprio(0);
                        float p0, p1, p2, p3;
                        if (dk2 == 0) {   // diagonal sub-tile: mask key>q
                            p0 = (qoff + 0 > m) ? 0.f : __expf(acc[0] * 0.125f);
                            p1 = (qoff + 1 > m) ? 0.f : __expf(acc[1] * 0.125f);
                            p2 = (qoff + 2 > m) ? 0.f : __expf(acc[2] * 0.125f);
                            p3 = (qoff + 3 > m) ? 0.f : __expf(acc[3] * 0.125f);
                        } else {
                            p0 = __expf(acc[0] * 0.125f);
                            p1 = __expf(acc[1] * 0.125f);
                            p2 = __expf(acc[2] * 0.125f);
                            p3 = __expf(acc[3] * 0.125f);
                        }
                        lsum += (p0 + p1) + (p2 + p3);
                        u.x = cvt_pk_bf16(p0, p1);
                        u.y = cvt_pk_bf16(p2, p3);
                    }
                    *(uint2*)&Ps[w][m * 64 +
                        (((ct * 2 + (gq >> 1)) ^ (m & 7)) << 3) + ((gq & 1) << 2)] = u;
                }

                // ---- P A-frags + PV ----
                bf16x8 pf0 = *(const bf16x8*)
                    &Ps[w][m * 64 + ((gq ^ (m & 7)) << 3)];
                bf16x8 pf1 = *(const bf16x8*)
                    &Ps[w][m * 64 + (((4 + gq) ^ (m & 7)) << 3)];
                __builtin_amdgcn_s_setprio(1);
                #pragma unroll
                for (int ct2 = 0; ct2 < 4; ++ct2) {
                    int row = ct2 * 16 + m;   // d index
                    bf16x8 vf0 = *(const bf16x8*)
                        &Vt_[row * 64 + ((gq ^ (row & 7)) << 3)];
                    o[ct2] = __builtin_amdgcn_mfma_f32_16x16x32_bf16(
                        pf0, vf0, o[ct2], 0, 0, 0);
                    bf16x8 vf1 = *(const bf16x8*)
                        &Vt_[row * 64 + (((4 + gq) ^ (row & 7)) << 3)];
                    o[ct2] = __builtin_amdgcn_mfma_f32_16x16x32_bf16(
                        pf1, vf1, o[ct2], 0, 0, 0);
                }
                __builtin_amdgcn_s_setprio(0);
            }
            if (pre) {   // write prefetched tiles into the other buffer
                int nb = cur ^ 1;
                *(bf16x8*)&Ks[nb][0][slot] = k0r;
                *(bf16x8*)&Ks[nb][1][slot] = k1r;
                *(bf16x8*)&Vt[nb][0][slot] = v0r;
                *(bf16x8*)&Vt[nb][1][slot] = v1r;
            }
            __syncthreads();
        }

        // epilogue: lsum lives at q=m; reduce over gq groups, redistribute
        float l = lsum;
        l += __shfl_xor(l, 16);
        l += __shfl_xor(l, 32);
        float inv[4];
        #pragma unroll
        for (int r = 0; r < 4; ++r)
            inv[r] = 1.0f / __shfl(l, qoff + r);   // q row = qb + qoff + r

        int qt_old = (q0 >> 6) + (w >> 2);   // 64-row tile index
        int wv_old = w & 3;
        size_t base = (size_t)b * Tn * En + (size_t)h * 64 + (size_t)qt_old * En
                    + wv_old * 16 + gq * 4;
        #pragma unroll
        for (int ct2 = 0; ct2 < 4; ++ct2) {
            int d = ct2 * 16 + m;
            #pragma unroll
            for (int r = 0; r < 4; ++r)
                cat[base + (size_t)d * 32 * En + r] = f2bfu(o[ct2][r] * inv[r]);
        }
    }
}

extern "C" void kernel_launch(void* const* d_in, const int* in_sizes, int n_in,
                              void* d_out, int out_size, void* d_ws, size_t ws_size,
                              hipStream_t stream) {
    const float* x     = (const float*)d_in[0];
    const float* Wq    = (const float*)d_in[1];
    const float* Wk    = (const float*)d_in[2];
    const float* Wv    = (const float*)d_in[3];
    const float* fc_w  = (const float*)d_in[4];
    const float* fc_b  = (const float*)d_in[5];
    const float* ln1_s = (const float*)d_in[6];
    const float* ln1_b = (const float*)d_in[7];
    const float* ln2_s = (const float*)d_in[8];
    const float* ln2_b = (const float*)d_in[9];
    const float* ff_w1 = (const float*)d_in[10];
    const float* ff_b1 = (const float*)d_in[11];
    const float* ff_w2 = (const float*)d_in[12];
    const float* ff_b2 = (const float*)d_in[13];
    float* out = (float*)d_out;
    (void)in_sizes; (void)n_in; (void)out_size; (void)ws_size;

    const size_t MB = 1048576;
    char* w8 = (char*)d_ws;
    ushort* S0   = (ushort*)(w8 + 0 * MB);    // xn_bf / cat_bf (8MB)
    ushort* kb   = (ushort*)(w8 + 8 * MB);    // k bf16 (8MB)
    ushort* vtb  = (ushort*)(w8 + 16 * MB);   // v^T bf16 [g][d][t] (8MB)
    ushort* qb   = (ushort*)(w8 + 24 * MB);   // q bf16 / ynb_bf (8MB)
    ushort* hb   = (ushort*)(w8 + 32 * MB);   // h bf16 (8MB)
    ushort* Pfc  = (ushort*)(w8 + 48 * MB);   // fc partials 2x8MB bf16
    ushort* y1   = (ushort*)(w8 + 48 * MB);   // gelu out bf16 (32MB) reuses Pfc
    ushort* Pff2 = (ushort*)(w8 + 0 * MB);    // ff2 partials 4x8MB (S0..qb dead)
    ushort* wqkv = (ushort*)(w8 + 80 * MB);   // [3072][1024] (6MB)
    ushort* wfc  = (ushort*)(w8 + 86 * MB);   // [1024][1024] (2MB)
    ushort* wf1  = (ushort*)(w8 + 88 * MB);   // [4096][1024] (8MB)
    ushort* wf2  = (ushort*)(w8 + 96 * MB);   // [1024][4096] (8MB) -> 104MB total

    // unified weight prep (all four transposes, one dispatch)
    prep_w<<<dim3(3072), 256, 0, stream>>>(
        Wq, Wk, Wv, fc_w, ff_w1, ff_w2, wqkv, wfc, wf1, wf2);

    // LN1 -> xn (bf16)
    ln_kernel<<<dim3(Mrows), 256, 0, stream>>>(x, ln1_s, ln1_b, S0);
    // QKV: [4096,1024] x [3072,1024]^T on 256^2 8-phase (grid 16x12)
    gemm256<2><<<dim3(16, 12), 512, 0, stream>>>(
        S0, En, wqkv, En, En, nullptr, nullptr, 0, qb, kb, vtb);
    // attention -> cat (bf16, quirk layout), reuses S0; 8-wave Q=128 blocks
    attn_mfma<<<dim3(Hn * Bn, 8), 512, 0, stream>>>(qb, kb, vtb, S0);
    // fc split-K=2 on old 128-tile kernel: bf16 partials (2 x 8MB at Pfc)
    gemm_bf16<3, 64><<<dim3(32, 16, 2), 256, 0, stream>>>(
        S0, En, wfc, En, En / 2, nullptr, Pfc, En, nullptr, nullptr, nullptr);
    // reduce + bias + resid(x) -> hb (bf16), fused LN2 -> ynb (qb)
    ln2_fuse<<<dim3(Mrows), 256, 0, stream>>>(
        Pfc, Pfc + (size_t)Mrows * En, fc_b, x, ln2_s, ln2_b, hb, qb);
    // ff1: y1 = gelu(ynb @ ff_w1 + ff_b1) on 256^2 8-phase (grid 16x16)
    gemm256<1><<<dim3(16, 16), 512, 0, stream>>>(
        qb, En, wf1, En, En, ff_b1, y1, 4 * En, nullptr, nullptr, nullptr);
    // ff2 split-K=4 on 256^2 8-phase (grid 16x4x4): bf16 partials 4x8MB
    gemm256<3><<<dim3(16, 4, 4), 512, 0, stream>>>(
        y1, 4 * En, wf2, 4 * En, En, nullptr, Pff2, En, nullptr, nullptr, nullptr);
    // reduce 4 partials + bias + resid(h bf16) -> out
    ff2_reduce4<<<dim3(Mrows), 256, 0, stream>>>(Pff2, ff_b2, hb, out);
}

// Round 7
// 305.342 us; speedup vs baseline: 1.0378x; 1.0378x over previous
//
#include <hip/hip_runtime.h>

// Transformer block. B=2 T=2048 E=1024 H=16 DH=64.
// R19 = R18 resubmit (container infra failure; audit of SCHED1 found no
// fault — uniform barriers, monotone waitcnts, verified vmcnt bookkeeping).
// R18: in-run A/B of gemm256 schedules. SCHED 0 = R17 4-phase (8 barriers +
// 4 full lgkm drains per K-tile). SCHED 1 = 2-section per K-tile with
// counted vmcnt kept (T4): S1 {read all 24 frags, stage A(t+1), lgkm(0),
// 32 MFMA mh0, barrier} S2 {stage B(t+2), 32 MFMA mh1 (regs already live,
// no drain), vmcnt(4), barrier}. 2 barriers + 1 drain per tile.
// ff1 stays SCHED0, ff2+qkv get SCHED1 -> rocprof compares identical work
// (256 blocks x NT=16) across schedules in the same run.
// Attention (R15 swapped-QK) and everything else unchanged.

#define En 1024
#define Hn 16
#define DHn 64
#define Bn 2
#define Tn 2048
#define Mrows 4096  // B*T

typedef __attribute__((ext_vector_type(8))) short bf16x8;
typedef __attribute__((ext_vector_type(4))) float f32x4;

__device__ __forceinline__ short f2bf(float f) {
    unsigned u = __float_as_uint(f);
    u += 0x7FFFu + ((u >> 16) & 1u);   // round-to-nearest-even
    return (short)(u >> 16);
}
__device__ __forceinline__ ushort f2bfu(float f) {
    unsigned u = __float_as_uint(f);
    u += 0x7FFFu + ((u >> 16) & 1u);
    return (ushort)(u >> 16);
}
__device__ __forceinline__ float bf2f(ushort u) {
    return __uint_as_float((unsigned)u << 16);
}
__device__ __forceinline__ unsigned cvt_pk_bf16(float lo, float hi) {
    unsigned r;
    asm("v_cvt_pk_bf16_f32 %0, %1, %2" : "=v"(r) : "v"(lo), "v"(hi));
    return r;
}

// gelu = 0.5*x*(1+tanh(u)) = x * t/(t+1), t = exp(2u); u = c*x + 0.044715*x^3
__device__ __forceinline__ float gelu_f(float x) {
    float u = 0.79788456080286535588f * x + 0.044715f * x * x * x;
    float t = __expf(2.0f * u);
    return x * t / (t + 1.0f);
}

// async global->LDS, 16B per lane; LDS dest = wave-uniform base + lane*16
__device__ __forceinline__ void load_lds16(const void* g, void* l) {
    __builtin_amdgcn_global_load_lds(
        (const __attribute__((address_space(1))) unsigned int*)(uintptr_t)g,
        (__attribute__((address_space(3))) unsigned int*)(uintptr_t)l,
        16, 0, 0);
}

// ---------------- LayerNorm: one block per row, bf16 out ----------------
__global__ __launch_bounds__(256) void ln_kernel(
    const float* __restrict__ in, const float* __restrict__ sc,
    const float* __restrict__ sh, ushort* __restrict__ out)
{
    int row = blockIdx.x;
    int tid = threadIdx.x;
    float4 v = ((const float4*)(in + (size_t)row * En))[tid];
    float s  = v.x + v.y + v.z + v.w;
    float s2 = v.x*v.x + v.y*v.y + v.z*v.z + v.w*v.w;
    #pragma unroll
    for (int off = 32; off > 0; off >>= 1) {
        s  += __shfl_down(s,  off);
        s2 += __shfl_down(s2, off);
    }
    __shared__ float red[2][4];
    int wave = tid >> 6, lane = tid & 63;
    if (lane == 0) { red[0][wave] = s; red[1][wave] = s2; }
    __syncthreads();
    s  = red[0][0] + red[0][1] + red[0][2] + red[0][3];
    s2 = red[1][0] + red[1][1] + red[1][2] + red[1][3];
    float mean = s * (1.0f / En);
    float var  = s2 * (1.0f / En) - mean * mean;
    float r = rsqrtf(var + 1e-5f);
    float4 scv = ((const float4*)sc)[tid];
    float4 shv = ((const float4*)sh)[tid];
    ushort4 o;
    o.x = f2bfu(scv.x * (v.x - mean) * r + shv.x);
    o.y = f2bfu(scv.y * (v.y - mean) * r + shv.y);
    o.z = f2bfu(scv.z * (v.z - mean) * r + shv.z);
    o.w = f2bfu(scv.w * (v.w - mean) * r + shv.w);
    ((ushort4*)(out + (size_t)row * En))[tid] = o;
}

// ---- fc split-K reduce (bf16 partials) + residual + LN2; h stored bf16 ----
__global__ __launch_bounds__(256) void ln2_fuse(
    const ushort* __restrict__ P0, const ushort* __restrict__ P1,
    const float* __restrict__ bias, const float* __restrict__ x,
    const float* __restrict__ sc, const float* __restrict__ sh,
    ushort* __restrict__ hb, ushort* __restrict__ ynb)
{
    int row = blockIdx.x, tid = threadIdx.x;
    size_t idx = (size_t)row * 256 + tid;
    ushort4 a = ((const ushort4*)P0)[idx];
    ushort4 b = ((const ushort4*)P1)[idx];
    float4 bi = ((const float4*)bias)[tid];
    float4 xr = ((const float4*)x)[idx];
    float4 v;
    v.x = bf2f(a.x) + bf2f(b.x) + bi.x + xr.x;
    v.y = bf2f(a.y) + bf2f(b.y) + bi.y + xr.y;
    v.z = bf2f(a.z) + bf2f(b.z) + bi.z + xr.z;
    v.w = bf2f(a.w) + bf2f(b.w) + bi.w + xr.w;
    ushort4 hv;
    hv.x = f2bfu(v.x); hv.y = f2bfu(v.y); hv.z = f2bfu(v.z); hv.w = f2bfu(v.w);
    ((ushort4*)hb)[idx] = hv;
    float s  = v.x + v.y + v.z + v.w;
    float s2 = v.x*v.x + v.y*v.y + v.z*v.z + v.w*v.w;
    #pragma unroll
    for (int off = 32; off > 0; off >>= 1) {
        s  += __shfl_down(s,  off);
        s2 += __shfl_down(s2, off);
    }
    __shared__ float red[2][4];
    int wave = tid >> 6, lane = tid & 63;
    if (lane == 0) { red[0][wave] = s; red[1][wave] = s2; }
    __syncthreads();
    s  = red[0][0] + red[0][1] + red[0][2] + red[0][3];
    s2 = red[1][0] + red[1][1] + red[1][2] + red[1][3];
    float mean = s * (1.0f / En);
    float var  = s2 * (1.0f / En) - mean * mean;
    float r = rsqrtf(var + 1e-5f);
    float4 scv = ((const float4*)sc)[tid];
    float4 shv = ((const float4*)sh)[tid];
    ushort4 o;
    o.x = f2bfu(scv.x * (v.x - mean) * r + shv.x);
    o.y = f2bfu(scv.y * (v.y - mean) * r + shv.y);
    o.z = f2bfu(scv.z * (v.z - mean) * r + shv.z);
    o.w = f2bfu(scv.w * (v.w - mean) * r + shv.w);
    ((ushort4*)ynb)[idx] = o;
}

// ---- ff2 split-K=4 reduce (bf16 partials) + bias + residual(bf16 h) -> out --
__global__ __launch_bounds__(256) void ff2_reduce4(
    const ushort* __restrict__ P, const float* __restrict__ bias,
    const ushort* __restrict__ hb, float* __restrict__ out)
{
    int tid = threadIdx.x;
    size_t i = (size_t)blockIdx.x * 256 + tid;
    const size_t S = (size_t)Mrows * En / 4;   // ushort4 per partial
    ushort4 a = ((const ushort4*)P)[i];
    ushort4 b = ((const ushort4*)P)[i + S];
    ushort4 c = ((const ushort4*)P)[i + 2 * S];
    ushort4 d = ((const ushort4*)P)[i + 3 * S];
    float4 bi = ((const float4*)bias)[tid];
    ushort4 hu = ((const ushort4*)hb)[i];
    float4 o;
    o.x = (bf2f(a.x) + bf2f(b.x)) + (bf2f(c.x) + bf2f(d.x)) + bi.x + bf2f(hu.x);
    o.y = (bf2f(a.y) + bf2f(b.y)) + (bf2f(c.y) + bf2f(d.y)) + bi.y + bf2f(hu.y);
    o.z = (bf2f(a.z) + bf2f(b.z)) + (bf2f(c.z) + bf2f(d.z)) + bi.z + bf2f(hu.z);
    o.w = (bf2f(a.w) + bf2f(b.w)) + (bf2f(c.w) + bf2f(d.w)) + bi.w + bf2f(hu.w);
    ((float4*)out)[i] = o;
}

// ------- unified weight prep: all four transposes in one dispatch ---------
// out[n*ldo + k] = bf16(in[k*N + n]), 64x64 tiles.
__global__ __launch_bounds__(256) void prep_w(
    const float* __restrict__ Wq, const float* __restrict__ Wk,
    const float* __restrict__ Wv, const float* __restrict__ fc_w,
    const float* __restrict__ ff_w1, const float* __restrict__ ff_w2,
    ushort* __restrict__ wqkv, ushort* __restrict__ wfc,
    ushort* __restrict__ wf1, ushort* __restrict__ wf2)
{
    int bid = blockIdx.x;
    const float* in; ushort* out; int N, ldo, k0, n0;
    if (bid < 768) {                       // qkv: 48 z-slices x 16 k-blocks
        int z = bid >> 4, kb = bid & 15;
        int sel = z / 16, h = z % 16;
        in  = (sel == 0 ? Wq : sel == 1 ? Wk : Wv) + (size_t)h * En * DHn;
        out = wqkv + (size_t)(sel * 1024 + h * 64) * En;
        N = DHn; ldo = En; k0 = kb * 64; n0 = 0;
    } else if (bid < 1024) {               // fc_w: 16x16
        int b2 = bid - 768;
        in = fc_w; out = wfc; N = En; ldo = En;
        k0 = (b2 & 15) * 64; n0 = (b2 >> 4) * 64;
    } else if (bid < 2048) {               // ff_w1: 16 k x 64 n
        int b2 = bid - 1024;
        in = ff_w1; out = wf1; N = 4 * En; ldo = En;
        k0 = (b2 & 15) * 64; n0 = (b2 >> 4) * 64;
    } else {                               // ff_w2: 64 k x 16 n
        int b2 = bid - 2048;
        in = ff_w2; out = wf2; N = En; ldo = 4 * En;
        k0 = (b2 & 63) * 64; n0 = (b2 >> 6) * 64;
    }
    __shared__ float t[64][65];
    int tid = threadIdx.x, r = tid >> 4, c4 = (tid & 15) * 4;
    #pragma unroll
    for (int i = 0; i < 4; ++i) {
        float4 v = *(const float4*)(in + (size_t)(k0 + r + i * 16) * N + n0 + c4);
        t[r + i * 16][c4 + 0] = v.x; t[r + i * 16][c4 + 1] = v.y;
        t[r + i * 16][c4 + 2] = v.z; t[r + i * 16][c4 + 3] = v.w;
    }
    __syncthreads();
    #pragma unroll
    for (int i = 0; i < 4; ++i) {
        int n = r + i * 16;
        ushort4 u;
        u.x = f2bfu(t[c4 + 0][n]); u.y = f2bfu(t[c4 + 1][n]);
        u.z = f2bfu(t[c4 + 2][n]); u.w = f2bfu(t[c4 + 3][n]);
        *(ushort4*)(out + (size_t)(n0 + n) * ldo + k0 + c4) = u;
    }
}

// ---------------- bf16 MFMA GEMM (old 128-tile): used for fc only ----------
template<int MODE, int TN>
__global__ __launch_bounds__(256) void gemm_bf16(
    const ushort* __restrict__ A, int lda,
    const ushort* __restrict__ Bt, int ldb, int Kloop,
    const float* __restrict__ bias,
    ushort* __restrict__ Cb, int ldc,
    ushort* __restrict__ qo, ushort* __restrict__ ko, ushort* __restrict__ vo)
{
    constexpr int WCN = TN / 2;        // wave n-extent
    constexpr int NI  = WCN / 16;      // 16-col blocks per wave
    constexpr int BIW = TN * 8 / 256;  // B staging instrs per wave
    constexpr int STAGE = 128 * 64 + TN * 64;
    constexpr int BOUNCE = (MODE == 2 || MODE == 1) ? 4 * 64 * 68
                         : (MODE == 3 ? 128 * 68 : 0);
    constexpr int SMEMN = STAGE > BOUNCE ? STAGE : BOUNCE;
    __shared__ ushort smem[SMEMN];
    ushort* As = smem;
    ushort* Bs = smem + 128 * 64;
    int tid = threadIdx.x, wv = tid >> 6, lid = tid & 63;
    int m0 = blockIdx.x * 128, n0 = blockIdx.y * TN;
    int koff = blockIdx.z * Kloop;
    int wr = wv >> 1, wc = wv & 1;
    int hm = lid & 15, hk = lid >> 4;

    f32x4 acc[4][NI];
    #pragma unroll
    for (int i = 0; i < 4; ++i)
        #pragma unroll
        for (int j = 0; j < NI; ++j) acc[i][j] = (f32x4){0.f, 0.f, 0.f, 0.f};

    const ushort* Abase = A + (size_t)m0 * lda + koff;
    const ushort* Bbase = Bt + (size_t)n0 * ldb + koff;

    for (int k0 = 0; k0 < Kloop; k0 += 64) {
        __syncthreads();
        #pragma unroll
        for (int i = 0; i < 4; ++i) {       // A: 1024 chunks, 4/lane
            int c = wv * 256 + i * 64 + lid;
            int r = c >> 3, s = c & 7;
            int j = s ^ (r & 7);            // source k-chunk for this LDS slot
            load_lds16(Abase + (size_t)r * lda + k0 + j * 8,
                       &As[(wv * 256 + i * 64) * 8]);
        }
        #pragma unroll
        for (int i = 0; i < BIW; ++i) {
            int c = wv * (BIW * 64) + i * 64 + lid;
            int r = c >> 3, s = c & 7;
            int j = s ^ (r & 7);
            load_lds16(Bbase + (size_t)r * ldb + k0 + j * 8,
                       &Bs[(wv * (BIW * 64) + i * 64) * 8]);
        }
        __syncthreads();
        #pragma unroll
        for (int kk = 0; kk < 2; ++kk) {
            bf16x8 af[4], bfr[NI];
            #pragma unroll
            for (int mi = 0; mi < 4; ++mi) {
                int r = wr * 64 + mi * 16 + hm;
                int slot = ((kk << 2) | hk) ^ (r & 7);
                af[mi] = *(const bf16x8*)&As[(r * 8 + slot) * 8];
            }
            #pragma unroll
            for (int ni = 0; ni < NI; ++ni) {
                int r = wc * WCN + ni * 16 + hm;
                int slot = ((kk << 2) | hk) ^ (r & 7);
                bfr[ni] = *(const bf16x8*)&Bs[(r * 8 + slot) * 8];
            }
            #pragma unroll
            for (int mi = 0; mi < 4; ++mi)
                #pragma unroll
                for (int ni = 0; ni < NI; ++ni)
                    acc[mi][ni] = __builtin_amdgcn_mfma_f32_16x16x32_bf16(
                        af[mi], bfr[ni], acc[mi][ni], 0, 0, 0);
        }
    }

    int colbase = n0 + wc * WCN + hm;
    if (MODE == 1) {
        __syncthreads();
        ushort* Ls = smem + wv * (64 * 68);
        #pragma unroll
        for (int ni = 0; ni < NI; ++ni) {
            int col = colbase + ni * 16;
            float bb = bias[col];
            #pragma unroll
            for (int mi = 0; mi < 4; ++mi)
                #pragma unroll
                for (int r = 0; r < 4; ++r)
                    Ls[(mi * 16 + hk * 4 + r) * 68 + ni * 16 + hm] =
                        f2bfu(gelu_f(acc[mi][ni][r] + bb));
        }
        ushort* outp = Cb + (size_t)(m0 + wr * 64) * ldc + n0 + wc * 64;
        int dcol = hm * 4;
        #pragma unroll
        for (int i = 0; i < 16; ++i) {
            int t = hk + i * 4;
            *(ushort4*)(outp + (size_t)t * ldc + dcol) =
                *(const ushort4*)&Ls[t * 68 + dcol];
        }
    } else if (MODE == 2) {
        __syncthreads();
        ushort* Ls = smem + wv * (64 * 68);
        int col0 = n0 + wc * 64;
        int sel = col0 >> 10, h = (col0 & 1023) >> 6;
        if (sel < 2) {
            #pragma unroll
            for (int ni = 0; ni < NI; ++ni)
                #pragma unroll
                for (int mi = 0; mi < 4; ++mi)
                    #pragma unroll
                    for (int r = 0; r < 4; ++r)
                        Ls[(mi * 16 + hk * 4 + r) * 68 + ni * 16 + hm] =
                            f2bfu(acc[mi][ni][r]);
            ushort* outp = (sel == 0 ? qo : ko) + (size_t)h * (Mrows * DHn);
            int dcol = hm * 4;
            #pragma unroll
            for (int i = 0; i < 16; ++i) {
                int t = hk + i * 4;
                *(ushort4*)(outp + (size_t)(m0 + wr * 64 + t) * DHn + dcol) =
                    *(const ushort4*)&Ls[t * 68 + dcol];
            }
        } else {
            #pragma unroll
            for (int ni = 0; ni < NI; ++ni)
                #pragma unroll
                for (int mi = 0; mi < 4; ++mi)
                    #pragma unroll
                    for (int r = 0; r < 4; ++r)
                        Ls[(ni * 16 + hm) * 68 + mi * 16 + hk * 4 + r] =
                            f2bfu(acc[mi][ni][r]);
            int bb2 = m0 >> 11;                 // batch of this row-tile
            int t0 = (m0 & 2047) + wr * 64;
            ushort* outp = vo + ((size_t)((h * 2 + bb2) * 64)) * Tn + t0;
            int tcol = hm * 4;
            #pragma unroll
            for (int i = 0; i < 16; ++i) {
                int d = hk + i * 4;
                *(ushort4*)(outp + (size_t)d * Tn + tcol) =
                    *(const ushort4*)&Ls[d * 68 + tcol];
            }
        }
    } else {
        __syncthreads();
        ushort* Ls = smem;
        #pragma unroll
        for (int ni = 0; ni < NI; ++ni)
            #pragma unroll
            for (int mi = 0; mi < 4; ++mi)
                #pragma unroll
                for (int r = 0; r < 4; ++r)
                    Ls[(wr * 64 + mi * 16 + hk * 4 + r) * 68
                       + wc * WCN + ni * 16 + hm] = f2bfu(acc[mi][ni][r]);
        __syncthreads();
        ushort* Cp = Cb + (size_t)blockIdx.z * Mrows * ldc;
        #pragma unroll
        for (int it = 0; it < 8; ++it) {
            int i = it * 1024 + tid * 4;
            int row = i >> 6, col = i & 63;
            *(ushort4*)(Cp + (size_t)(m0 + row) * ldc + n0 + col) =
                *(const ushort4*)&Ls[row * 68 + col];
        }
    }
}

// ============ gemm256: 256x256 tile, BK=64, two schedules ==========
#define PHASE_MID() do { \
    __builtin_amdgcn_s_barrier(); \
    asm volatile("s_waitcnt lgkmcnt(0)" ::: "memory"); \
} while (0)

#define MFMA_HALF(MH, KK) \
    _Pragma("unroll") \
    for (int mi = 0; mi < 4; ++mi) \
        _Pragma("unroll") \
        for (int ni = 0; ni < 4; ++ni) \
            acc[(MH) * 4 + mi][ni] = __builtin_amdgcn_mfma_f32_16x16x32_bf16( \
                af[MH][KK][mi], bfr[KK][ni], acc[(MH) * 4 + mi][ni], 0, 0, 0);

#define STAGE_A(bufp, h, ksrc) do { \
    ushort* _d = smem + (bufp) * 32768; \
    load_lds16(Abase + aoff[h][0] + (ksrc), _d + ldsoff[h][0]); \
    load_lds16(Abase + aoff[h][1] + (ksrc), _d + ldsoff[h][1]); \
} while (0)

#define STAGE_B(bufp, h, ksrc) do { \
    ushort* _d = smem + (bufp) * 32768 + 16384; \
    load_lds16(Bbase + boff[h][0] + (ksrc), _d + ldsoff[h][0]); \
    load_lds16(Bbase + boff[h][1] + (ksrc), _d + ldsoff[h][1]); \
} while (0)

// MODE 1: Cb = bf16(gelu(acc + bias)) row-major [M][ldc]
// MODE 2: qkv scatter (q/k [h][t][d], v^T [g][d][t])
// MODE 3: bf16 split-K partial at Cb + z*Mrows*ldc
// SCHED 0: 4-phase (R17). SCHED 1: 2-section, counted vmcnt kept.
template<int MODE, int SCHED>
__global__ __launch_bounds__(512, 2) void gemm256(
    const ushort* __restrict__ A, int lda,
    const ushort* __restrict__ Bt, int ldb, int Kloop,
    const float* __restrict__ bias,
    ushort* __restrict__ Cb, int ldc,
    ushort* __restrict__ qo, ushort* __restrict__ ko, ushort* __restrict__ vo)
{
    __shared__ ushort smem[65536];   // 128 KiB
    int tid = threadIdx.x, wv = tid >> 6, lid = tid & 63;
    int wr = wv >> 2, wc = wv & 3;           // 2M x 4N waves
    int hm = lid & 15, hk = lid >> 4;
    int m0 = blockIdx.x * 256, n0 = blockIdx.y * 256;
    int koff = blockIdx.z * Kloop;
    int NT = Kloop >> 6;

    const ushort* Abase = A + (size_t)m0 * lda + koff;
    const ushort* Bbase = Bt + (size_t)n0 * ldb + koff;

    // per-thread staging offsets: half h, instr i -> chunk c, row r, slot s
    int aoff[2][2], boff[2][2], ldsoff[2][2];
    #pragma unroll
    for (int h = 0; h < 2; ++h)
        #pragma unroll
        for (int i = 0; i < 2; ++i) {
            int c = h * 1024 + wv * 128 + i * 64 + lid;
            int r = c >> 3, s = c & 7, j = s ^ (r & 7);
            aoff[h][i] = r * lda + j * 8;
            boff[h][i] = r * ldb + j * 8;
            ldsoff[h][i] = (h * 1024 + wv * 128 + i * 64) * 8;  // wave-uniform
        }

    // precomputed swizzled LDS read offsets (all statically indexed)
    int offA[2][2][4], offB[2][4];
    #pragma unroll
    for (int mh = 0; mh < 2; ++mh)
        #pragma unroll
        for (int kk = 0; kk < 2; ++kk)
            #pragma unroll
            for (int mi = 0; mi < 4; ++mi) {
                int r = wr * 128 + mh * 64 + mi * 16 + hm;
                offA[mh][kk][mi] = (r * 8 + (((kk << 2) | hk) ^ (r & 7))) * 8;
            }
    #pragma unroll
    for (int kk = 0; kk < 2; ++kk)
        #pragma unroll
        for (int ni = 0; ni < 4; ++ni) {
            int r = wc * 64 + ni * 16 + hm;
            offB[kk][ni] = (r * 8 + (((kk << 2) | hk) ^ (r & 7))) * 8;
        }

    f32x4 acc[8][4];
    #pragma unroll
    for (int i = 0; i < 8; ++i)
        #pragma unroll
        for (int j = 0; j < 4; ++j) acc[i][j] = (f32x4){0.f, 0.f, 0.f, 0.f};

    // prologue: A0, B0 -> buf0; B1 -> buf1; allow B1 (4 loads) outstanding
    STAGE_A(0, 0, 0); STAGE_A(0, 1, 0);
    STAGE_B(0, 0, 0); STAGE_B(0, 1, 0);
    {
        int k1 = (NT > 1 ? 1 : 0) << 6;
        STAGE_B(1, 0, k1); STAGE_B(1, 1, k1);
    }
    asm volatile("s_waitcnt vmcnt(4)" ::: "memory");
    __builtin_amdgcn_s_barrier();

    for (int t = 0; t < NT; ++t) {
        int cur = t & 1, nxt = cur ^ 1;
        int kA = (t + 1 < NT ? t + 1 : NT - 1) << 6;   // clamp: tail issues
        int kB = (t + 2 < NT ? t + 2 : NT - 1) << 6;   // harmless re-reads
        const ushort* As_ = smem + cur * 32768;
        const ushort* Bs_ = As_ + 16384;

        if (SCHED == 0) {
            bf16x8 af[2][2][4], bfr[2][4];
            // ---- phase 1: mh0 x kk0; read all B frags; stage A(t+1) h0 ----
            #pragma unroll
            for (int mi = 0; mi < 4; ++mi)
                af[0][0][mi] = *(const bf16x8*)&As_[offA[0][0][mi]];
            #pragma unroll
            for (int kk = 0; kk < 2; ++kk)
                #pragma unroll
                for (int ni = 0; ni < 4; ++ni)
                    bfr[kk][ni] = *(const bf16x8*)&Bs_[offB[kk][ni]];
            STAGE_A(nxt, 0, kA);
            PHASE_MID();
            __builtin_amdgcn_s_setprio(1);
            MFMA_HALF(0, 0);
            __builtin_amdgcn_s_setprio(0);
            __builtin_amdgcn_s_barrier();

            // ---- phase 2: mh1 x kk0; stage A(t+1) h1 ----
            #pragma unroll
            for (int mi = 0; mi < 4; ++mi)
                af[1][0][mi] = *(const bf16x8*)&As_[offA[1][0][mi]];
            STAGE_A(nxt, 1, kA);
            PHASE_MID();
            __builtin_amdgcn_s_setprio(1);
            MFMA_HALF(1, 0);
            __builtin_amdgcn_s_setprio(0);
            __builtin_amdgcn_s_barrier();

            // ---- phase 3: mh0 x kk1; stage B(t+2) h0 ----
            #pragma unroll
            for (int mi = 0; mi < 4; ++mi)
                af[0][1][mi] = *(const bf16x8*)&As_[offA[0][1][mi]];
            STAGE_B(cur, 0, kB);
            PHASE_MID();
            __builtin_amdgcn_s_setprio(1);
            MFMA_HALF(0, 1);
            __builtin_amdgcn_s_setprio(0);
            __builtin_amdgcn_s_barrier();

            // ---- phase 4: mh1 x kk1; stage B(t+2) h1; counted wait ----
            #pragma unroll
            for (int mi = 0; mi < 4; ++mi)
                af[1][1][mi] = *(const bf16x8*)&As_[offA[1][1][mi]];
            STAGE_B(cur, 1, kB);
            PHASE_MID();
            __builtin_amdgcn_s_setprio(1);
            MFMA_HALF(1, 1);
            __builtin_amdgcn_s_setprio(0);
            asm volatile("s_waitcnt vmcnt(4)" ::: "memory");
            __builtin_amdgcn_s_barrier();
        } else {
            bf16x8 af[2][2][4], bfr[2][4];
            // ---- S1: read ALL 24 frags; stage A(t+1); 32 MFMA (mh0) ----
            #pragma unroll
            for (int kk = 0; kk < 2; ++kk) {
                #pragma unroll
                for (int ni = 0; ni < 4; ++ni)
                    bfr[kk][ni] = *(const bf16x8*)&Bs_[offB[kk][ni]];
                #pragma unroll
                for (int mh = 0; mh < 2; ++mh)
                    #pragma unroll
                    for (int mi = 0; mi < 4; ++mi)
                        af[mh][kk][mi] = *(const bf16x8*)&As_[offA[mh][kk][mi]];
            }
            STAGE_A(nxt, 0, kA);
            STAGE_A(nxt, 1, kA);
            asm volatile("s_waitcnt lgkmcnt(0)" ::: "memory");
            __builtin_amdgcn_s_setprio(1);
            MFMA_HALF(0, 0);
            MFMA_HALF(0, 1);
            __builtin_amdgcn_s_setprio(0);
            __builtin_amdgcn_s_barrier();   // all waves' reads drained here

            // ---- S2: stage B(t+2) (safe now); 32 MFMA (mh1); counted wait --
            STAGE_B(cur, 0, kB);
            STAGE_B(cur, 1, kB);
            __builtin_amdgcn_s_setprio(1);
            MFMA_HALF(1, 0);
            MFMA_HALF(1, 1);
            __builtin_amdgcn_s_setprio(0);
            asm volatile("s_waitcnt vmcnt(4)" ::: "memory");
            __builtin_amdgcn_s_barrier();   // A(t+1) landed for all waves
        }
    }
    // drain trailing (garbage) stages before LDS reuse by epilogue
    asm volatile("s_waitcnt vmcnt(0)" ::: "memory");
    __builtin_amdgcn_s_barrier();

    // ---------------- epilogues: per-wave 64x68 LDS bounce, 2 chunks -------
    ushort* Ls = smem + wv * (64 * 68);
    int dcol = hm * 4;
    if (MODE == 1) {
        float bb[4];
        #pragma unroll
        for (int ni = 0; ni < 4; ++ni) bb[ni] = bias[n0 + wc * 64 + ni * 16 + hm];
        #pragma unroll
        for (int mh = 0; mh < 2; ++mh) {
            #pragma unroll
            for (int ni = 0; ni < 4; ++ni)
                #pragma unroll
                for (int mi = 0; mi < 4; ++mi)
                    #pragma unroll
                    for (int r = 0; r < 4; ++r)
                        Ls[(mi * 16 + hk * 4 + r) * 68 + ni * 16 + hm] =
                            f2bfu(gelu_f(acc[mh * 4 + mi][ni][r] + bb[ni]));
            ushort* outp = Cb + (size_t)(m0 + wr * 128 + mh * 64) * ldc
                              + n0 + wc * 64;
            #pragma unroll
            for (int i = 0; i < 16; ++i) {
                int tt = hk + i * 4;
                *(ushort4*)(outp + (size_t)tt * ldc + dcol) =
                    *(const ushort4*)&Ls[tt * 68 + dcol];
            }
        }
    } else if (MODE == 2) {
        int col0 = n0 + wc * 64;
        int sel = col0 >> 10, hh = (col0 & 1023) >> 6;
        #pragma unroll
        for (int mh = 0; mh < 2; ++mh) {
            int rowb = m0 + wr * 128 + mh * 64;
            if (sel < 2) {
                #pragma unroll
                for (int ni = 0; ni < 4; ++ni)
                    #pragma unroll
                    for (int mi = 0; mi < 4; ++mi)
                        #pragma unroll
                        for (int r = 0; r < 4; ++r)
                            Ls[(mi * 16 + hk * 4 + r) * 68 + ni * 16 + hm] =
                                f2bfu(acc[mh * 4 + mi][ni][r]);
                ushort* outp = (sel == 0 ? qo : ko) + (size_t)hh * (Mrows * DHn);
                #pragma unroll
                for (int i = 0; i < 16; ++i) {
                    int tt = hk + i * 4;
                    *(ushort4*)(outp + (size_t)(rowb + tt) * DHn + dcol) =
                        *(const ushort4*)&Ls[tt * 68 + dcol];
                }
            } else {
                #pragma unroll
                for (int ni = 0; ni < 4; ++ni)
                    #pragma unroll
                    for (int mi = 0; mi < 4; ++mi)
                        #pragma unroll
                        for (int r = 0; r < 4; ++r)
                            Ls[(ni * 16 + hm) * 68 + mi * 16 + hk * 4 + r] =
                                f2bfu(acc[mh * 4 + mi][ni][r]);
                int bb2 = m0 >> 11;
                int t0 = (m0 & 2047) + wr * 128 + mh * 64;
                ushort* outp = vo + ((size_t)((hh * 2 + bb2) * 64)) * Tn + t0;
                #pragma unroll
                for (int i = 0; i < 16; ++i) {
                    int d = hk + i * 4;
                    *(ushort4*)(outp + (size_t)d * Tn + dcol) =
                        *(const ushort4*)&Ls[d * 68 + dcol];
                }
            }
        }
    } else {
        ushort* Cp = Cb + (size_t)blockIdx.z * ((size_t)Mrows * ldc);
        #pragma unroll
        for (int mh = 0; mh < 2; ++mh) {
            #pragma unroll
            for (int ni = 0; ni < 4; ++ni)
                #pragma unroll
                for (int mi = 0; mi < 4; ++mi)
                    #pragma unroll
                    for (int r = 0; r < 4; ++r)
                        Ls[(mi * 16 + hk * 4 + r) * 68 + ni * 16 + hm] =
                            f2bfu(acc[mh * 4 + mi][ni][r]);
            ushort* outp = Cp + (size_t)(m0 + wr * 128 + mh * 64) * ldc
                              + n0 + wc * 64;
            #pragma unroll
            for (int i = 0; i < 16; ++i) {
                int tt = hk + i * 4;
                *(ushort4*)(outp + (size_t)tt * ldc + dcol) =
                    *(const ushort4*)&Ls[tt * 68 + dcol];
            }
        }
    }
}

// ======== MFMA flash attention v5: swapped QK^T + packed P bounce ==========
__global__ __launch_bounds__(512) void attn_mfma(
    const ushort* __restrict__ q, const ushort* __restrict__ ksrc,
    const ushort* __restrict__ vtsrc, ushort* __restrict__ cat)
{
    int g = blockIdx.x;
    int h = g >> 1, b = g & 1;
    const ushort* qg  = q     + (size_t)g * Tn * DHn;
    const ushort* kg  = ksrc  + (size_t)g * Tn * DHn;
    const ushort* vtg = vtsrc + (size_t)g * DHn * Tn;   // [d][t]
    int tid = threadIdx.x, w = tid >> 6, lane = tid & 63;
    int m = lane & 15, gq = lane >> 4;
    int qoff = gq * 4;

    __shared__ short Ks[2][2][4096];   // [buf][tile-half][key(64)][d(64)] swz
    __shared__ short Vt[2][2][4096];   // [buf][tile-half][d(64)][key(64)] swz
    __shared__ short Ps[8][1024];      // per-wave [q(16)][key(64)] swz

    int R = tid >> 3;    // staging row 0..63
    int c = tid & 7;     // staging 8-ushort chunk
    int slot = R * 64 + ((c ^ (R & 7)) << 3);
    const ushort* kbase = kg  + (size_t)R * DHn + c * 8;  // + kt*4096
    const ushort* vbase = vtg + (size_t)R * Tn  + c * 8;  // + kt*64

    #pragma unroll 1
    for (int phase = 0; phase < 2; ++phase) {
        int qj = phase ? (15 - (int)blockIdx.y) : (int)blockIdx.y;
        int q0 = qj * 128;
        int NR = qj + 1;                 // rounds of 2 k-tiles
        int qb = q0 + w * 16;            // wave's first q row

        bf16x8 qf[2];
        {
            const ushort* qp = qg + (size_t)(qb + m) * DHn + gq * 8;
            qf[0] = *(const bf16x8*)(qp);
            qf[1] = *(const bf16x8*)(qp + 32);
        }
        f32x4 o[4];
        #pragma unroll
        for (int i = 0; i < 4; ++i) o[i] = (f32x4){0.f, 0.f, 0.f, 0.f};
        float lsum = 0.f;

        // prologue: stage tiles 0,1 into buf0
        {
            bf16x8 a0 = *(const bf16x8*)(kbase);
            bf16x8 a1 = *(const bf16x8*)(kbase + 4096);
            bf16x8 b0 = *(const bf16x8*)(vbase);
            bf16x8 b1 = *(const bf16x8*)(vbase + 64);
            *(bf16x8*)&Ks[0][0][slot] = a0;
            *(bf16x8*)&Ks[0][1][slot] = a1;
            *(bf16x8*)&Vt[0][0][slot] = b0;
            *(bf16x8*)&Vt[0][1][slot] = b1;
        }
        __syncthreads();

        #pragma unroll 1
        for (int rd = 0; rd < NR; ++rd) {
            int cur = rd & 1;
            bf16x8 k0r, k1r, v0r, v1r;
            bool pre = (rd + 1 < NR);
            if (pre) {   // issue prefetch BEFORE compute (T14)
                k0r = *(const bf16x8*)(kbase + (size_t)(2 * rd + 2) * 4096);
                k1r = *(const bf16x8*)(kbase + (size_t)(2 * rd + 3) * 4096);
                v0r = *(const bf16x8*)(vbase + (2 * rd + 2) * 64);
                v1r = *(const bf16x8*)(vbase + (2 * rd + 3) * 64);
            }
            #pragma unroll
            for (int hf = 0; hf < 2; ++hf) {
                int kt = 2 * rd + hf;
                const short* Kt_ = &Ks[cur][hf][0];
                const short* Vt_ = &Vt[cur][hf][0];
                if (qb < kt * 64) continue;   // wave fully masked here

                // ---- QK^T swapped: P[key][q], 4 consecutive keys/lane ----
                #pragma unroll
                for (int ct = 0; ct < 4; ++ct) {
                    int dk2 = kt * 64 + ct * 16 - qb;   // wave-uniform, %16==0
                    uint2 u;
                    if (dk2 > 0) {
                        u.x = 0u; u.y = 0u;
                    } else {
                        f32x4 acc = (f32x4){0.f, 0.f, 0.f, 0.f};
                        int row = ct * 16 + m;     // key within tile
                        __builtin_amdgcn_s_setprio(1);
                        #pragma unroll
                        for (int db = 0; db < 2; ++db) {
                            bf16x8 kf = *(const bf16x8*)
                                &Kt_[row * 64 + (((db * 4 + gq) ^ (row & 7)) << 3)];
                            acc = __builtin_amdgcn_mfma_f32_16x16x32_bf16(
                                kf, qf[db], acc, 0, 0, 0);
                        }
                        __builtin_amdgcn_s_setprio(0);
                        float p0, p1, p2, p3;
                        if (dk2 == 0) {   // diagonal sub-tile: mask key>q
                            p0 = (qoff + 0 > m) ? 0.f : __expf(acc[0] * 0.125f);
                            p1 = (qoff + 1 > m) ? 0.f : __expf(acc[1] * 0.125f);
                            p2 = (qoff + 2 > m) ? 0.f : __expf(acc[2] * 0.125f);
                            p3 = (qoff + 3 > m) ? 0.f : __expf(acc[3] * 0.125f);
                        } else {
                            p0 = __expf(acc[0] * 0.125f);
                            p1 = __expf(acc[1] * 0.125f);
                            p2 = __expf(acc[2] * 0.125f);
                            p3 = __expf(acc[3] * 0.125f);
                        }
                        lsum += (p0 + p1) + (p2 + p3);
                        u.x = cvt_pk_bf16(p0, p1);
                        u.y = cvt_pk_bf16(p2, p3);
                    }
                    *(uint2*)&Ps[w][m * 64 +
                        (((ct * 2 + (gq >> 1)) ^ (m & 7)) << 3) + ((gq & 1) << 2)] = u;
                }

                // ---- P A-frags + PV ----
                bf16x8 pf0 = *(const bf16x8*)
                    &Ps[w][m * 64 + ((gq ^ (m & 7)) << 3)];
                bf16x8 pf1 = *(const bf16x8*)
                    &Ps[w][m * 64 + (((4 + gq) ^ (m & 7)) << 3)];
                __builtin_amdgcn_s_setprio(1);
                #pragma unroll
                for (int ct2 = 0; ct2 < 4; ++ct2) {
                    int row = ct2 * 16 + m;   // d index
                    bf16x8 vf0 = *(const bf16x8*)
                        &Vt_[row * 64 + ((gq ^ (row & 7)) << 3)];
                    o[ct2] = __builtin_amdgcn_mfma_f32_16x16x32_bf16(
                        pf0, vf0, o[ct2], 0, 0, 0);
                    bf16x8 vf1 = *(const bf16x8*)
                        &Vt_[row * 64 + (((4 + gq) ^ (row & 7)) << 3)];
                    o[ct2] = __builtin_amdgcn_mfma_f32_16x16x32_bf16(
                        pf1, vf1, o[ct2], 0, 0, 0);
                }
                __builtin_amdgcn_s_setprio(0);
            }
            if (pre) {   // write prefetched tiles into the other buffer
                int nb = cur ^ 1;
                *(bf16x8*)&Ks[nb][0][slot] = k0r;
                *(bf16x8*)&Ks[nb][1][slot] = k1r;
                *(bf16x8*)&Vt[nb][0][slot] = v0r;
                *(bf16x8*)&Vt[nb][1][slot] = v1r;
            }
            __syncthreads();
        }

        // epilogue: lsum lives at q=m; reduce over gq groups, redistribute
        float l = lsum;
        l += __shfl_xor(l, 16);
        l += __shfl_xor(l, 32);
        float inv[4];
        #pragma unroll
        for (int r = 0; r < 4; ++r)
            inv[r] = 1.0f / __shfl(l, qoff + r);   // q row = qb + qoff + r

        int qt_old = (q0 >> 6) + (w >> 2);   // 64-row tile index
        int wv_old = w & 3;
        size_t base = (size_t)b * Tn * En + (size_t)h * 64 + (size_t)qt_old * En
                    + wv_old * 16 + gq * 4;
        #pragma unroll
        for (int ct2 = 0; ct2 < 4; ++ct2) {
            int d = ct2 * 16 + m;
            #pragma unroll
            for (int r = 0; r < 4; ++r)
                cat[base + (size_t)d * 32 * En + r] = f2bfu(o[ct2][r] * inv[r]);
        }
    }
}

extern "C" void kernel_launch(void* const* d_in, const int* in_sizes, int n_in,
                              void* d_out, int out_size, void* d_ws, size_t ws_size,
                              hipStream_t stream) {
    const float* x     = (const float*)d_in[0];
    const float* Wq    = (const float*)d_in[1];
    const float* Wk    = (const float*)d_in[2];
    const float* Wv    = (const float*)d_in[3];
    const float* fc_w  = (const float*)d_in[4];
    const float* fc_b  = (const float*)d_in[5];
    const float* ln1_s = (const float*)d_in[6];
    const float* ln1_b = (const float*)d_in[7];
    const float* ln2_s = (const float*)d_in[8];
    const float* ln2_b = (const float*)d_in[9];
    const float* ff_w1 = (const float*)d_in[10];
    const float* ff_b1 = (const float*)d_in[11];
    const float* ff_w2 = (const float*)d_in[12];
    const float* ff_b2 = (const float*)d_in[13];
    float* out = (float*)d_out;
    (void)in_sizes; (void)n_in; (void)out_size; (void)ws_size;

    const size_t MB = 1048576;
    char* w8 = (char*)d_ws;
    ushort* S0   = (ushort*)(w8 + 0 * MB);    // xn_bf / cat_bf (8MB)
    ushort* kb   = (ushort*)(w8 + 8 * MB);    // k bf16 (8MB)
    ushort* vtb  = (ushort*)(w8 + 16 * MB);   // v^T bf16 [g][d][t] (8MB)
    ushort* qb   = (ushort*)(w8 + 24 * MB);   // q bf16 / ynb_bf (8MB)
    ushort* hb   = (ushort*)(w8 + 32 * MB);   // h bf16 (8MB)
    ushort* Pfc  = (ushort*)(w8 + 48 * MB);   // fc partials 2x8MB bf16
    ushort* y1   = (ushort*)(w8 + 48 * MB);   // gelu out bf16 (32MB) reuses Pfc
    ushort* Pff2 = (ushort*)(w8 + 0 * MB);    // ff2 partials 4x8MB (S0..qb dead)
    ushort* wqkv = (ushort*)(w8 + 80 * MB);   // [3072][1024] (6MB)
    ushort* wfc  = (ushort*)(w8 + 86 * MB);   // [1024][1024] (2MB)
    ushort* wf1  = (ushort*)(w8 + 88 * MB);   // [4096][1024] (8MB)
    ushort* wf2  = (ushort*)(w8 + 96 * MB);   // [1024][4096] (8MB) -> 104MB total

    // unified weight prep (all four transposes, one dispatch)
    prep_w<<<dim3(3072), 256, 0, stream>>>(
        Wq, Wk, Wv, fc_w, ff_w1, ff_w2, wqkv, wfc, wf1, wf2);

    // LN1 -> xn (bf16)
    ln_kernel<<<dim3(Mrows), 256, 0, stream>>>(x, ln1_s, ln1_b, S0);
    // QKV on 2-section schedule (SCHED 1)
    gemm256<2, 1><<<dim3(16, 12), 512, 0, stream>>>(
        S0, En, wqkv, En, En, nullptr, nullptr, 0, qb, kb, vtb);
    // attention -> cat (bf16, quirk layout), reuses S0; 8-wave Q=128 blocks
    attn_mfma<<<dim3(Hn * Bn, 8), 512, 0, stream>>>(qb, kb, vtb, S0);
    // fc split-K=2 on old 128-tile kernel: bf16 partials (2 x 8MB at Pfc)
    gemm_bf16<3, 64><<<dim3(32, 16, 2), 256, 0, stream>>>(
        S0, En, wfc, En, En / 2, nullptr, Pfc, En, nullptr, nullptr, nullptr);
    // reduce + bias + resid(x) -> hb (bf16), fused LN2 -> ynb (qb)
    ln2_fuse<<<dim3(Mrows), 256, 0, stream>>>(
        Pfc, Pfc + (size_t)Mrows * En, fc_b, x, ln2_s, ln2_b, hb, qb);
    // ff1 on 4-phase schedule (SCHED 0) -> in-run A/B vs ff2's SCHED 1
    gemm256<1, 0><<<dim3(16, 16), 512, 0, stream>>>(
        qb, En, wf1, En, En, ff_b1, y1, 4 * En, nullptr, nullptr, nullptr);
    // ff2 split-K=4 on 2-section schedule (SCHED 1): grid 16x4x4 = 256 blocks
    gemm256<3, 1><<<dim3(16, 4, 4), 512, 0, stream>>>(
        y1, 4 * En, wf2, 4 * En, En, nullptr, Pff2, En, nullptr, nullptr, nullptr);
    // reduce 4 partials + bias + resid(h bf16) -> out
    ff2_reduce4<<<dim3(Mrows), 256, 0, stream>>>(Pff2, ff_b2, hb, out);
}